// Round 5
// baseline (464.661 us; speedup 1.0000x reference)
//
#include <hip/hip_runtime.h>
#include <stdint.h>

// B=8, N=4096, C=768, H=8, hd=96. bf16 MFMA path.
// G-route: S_bh = Wq_h^T G_b Wk_h with G_b = x_b^T x_b; normsq = diag products.
// Eliminates q/k materialization (qkT) and the N=4096 attn_s reduction.
// v path (gemm_v 256^2 8-phase), attn_v, gemm_out unchanged from passing R4 kernel.

typedef __attribute__((ext_vector_type(8))) __bf16 bf16x8;
typedef __attribute__((ext_vector_type(4))) float f32x4;

__device__ __forceinline__ unsigned short f2b(float f) {
  uint32_t u = __float_as_uint(f);
  u += 0x7FFF + ((u >> 16) & 1);
  return (unsigned short)(u >> 16);
}

__device__ __forceinline__ void gload16(const void* g, void* l) {
  __builtin_amdgcn_global_load_lds(
      (__attribute__((address_space(1))) void*)(uintptr_t)g,
      (__attribute__((address_space(3))) void*)(uintptr_t)l, 16, 0, 0);
}

__device__ __forceinline__ float dot8(const unsigned short* a, const unsigned short* b) {
  uint4 va = *(const uint4*)a, vb = *(const uint4*)b;
  const unsigned short* pa = (const unsigned short*)&va;
  const unsigned short* pb = (const unsigned short*)&vb;
  float s = 0.f;
#pragma unroll
  for (int i = 0; i < 8; i++)
    s += __uint_as_float((uint32_t)pa[i] << 16) * __uint_as_float((uint32_t)pb[i] << 16);
  return s;
}

// ---------------- cvt: x -> xb [bn][c] and xbT [b][c][n] (one x read) ----------------
__global__ void cvt_x(const float* __restrict__ in, unsigned short* __restrict__ xb,
                      unsigned short* __restrict__ xbT) {
  __shared__ float tile[32][33];
  int bx = blockIdx.x, by = blockIdx.y, b = blockIdx.z;
  int tx = threadIdx.x & 31, ty = threadIdx.x >> 5;
  const float* src = in + (size_t)b * 4096 * 768;
  for (int r = ty; r < 32; r += 8) {
    float v = src[(size_t)(by * 32 + r) * 768 + bx * 32 + tx];
    tile[r][tx] = v;
    xb[((size_t)b * 4096 + by * 32 + r) * 768 + bx * 32 + tx] = f2b(v);
  }
  __syncthreads();
  for (int r = ty; r < 32; r += 8)
    xbT[((size_t)b * 768 + bx * 32 + r) * 4096 + by * 32 + tx] = f2b(tile[tx][r]);
}

__global__ void cvt_transpose(const float* __restrict__ in, unsigned short* __restrict__ out,
                              int K, int NC) {
  __shared__ float tile[32][33];
  int bx = blockIdx.x, by = blockIdx.y;
  int tx = threadIdx.x & 31, ty = threadIdx.x >> 5;
  for (int r = ty; r < 32; r += 8)
    tile[r][tx] = in[(size_t)(by * 32 + r) * NC + bx * 32 + tx];
  __syncthreads();
  for (int r = ty; r < 32; r += 8)
    out[(size_t)(bx * 32 + r) * K + by * 32 + tx] = f2b(tile[tx][r]);
}

// ---------------- gemm_v: vT = (x @ Wv) scattered, 256^2 8-phase ----------------
#define BARX() asm volatile("s_barrier" ::: "memory")
#define WAITV(N) asm volatile("s_waitcnt vmcnt(" #N ")" ::: "memory")
#define SCHED() __builtin_amdgcn_sched_barrier(0)

#define STAGE(gbase, p, isB, h, t) do {                                             \
  unsigned short* _lb = &lds[(p)*32768 + (isB)*16384 + (h)*8192 + wid*1024];        \
  const unsigned short* _gb = (gbase) + (size_t)((h)*128 + wid*16)*768 + (t)*64 + lanegoff; \
  gload16(_gb, _lb);                                                                \
  gload16(_gb + 8*768, _lb + 512);                                                  \
} while (0)

#define LOAD_A(p, mh) do {                                                          \
  const unsigned short* _ab = &lds[(p)*32768 + (mh)*8192];                          \
  _Pragma("unroll") for (int _mi = 0; _mi < 4; _mi++)                               \
    _Pragma("unroll") for (int _kk = 0; _kk < 2; _kk++)                             \
      af[_mi][_kk] = *(const bf16x8*)&_ab[(wm*64 + _mi*16 + l16)*64 + ((_kk*4+quad)^(l16&7))*8]; \
} while (0)

#define LOAD_B(dst, p, nh) do {                                                     \
  const unsigned short* _bb = &lds[(p)*32768 + 16384 + (nh)*8192];                  \
  _Pragma("unroll") for (int _ni = 0; _ni < 2; _ni++)                               \
    _Pragma("unroll") for (int _kk = 0; _kk < 2; _kk++)                             \
      dst[_ni][_kk] = *(const bf16x8*)&_bb[(wn*32 + _ni*16 + l16)*64 + ((_kk*4+quad)^(l16&7))*8]; \
} while (0)

#define MFMA_PH(mh, nh, bfx) do {                                                   \
  __builtin_amdgcn_s_setprio(1);                                                    \
  _Pragma("unroll") for (int _m = 0; _m < 4; _m++)                                  \
    _Pragma("unroll") for (int _n = 0; _n < 2; _n++)                                \
      _Pragma("unroll") for (int _k = 0; _k < 2; _k++)                              \
        acc[(mh)*4+_m][(nh)*2+_n] = __builtin_amdgcn_mfma_f32_16x16x32_bf16(        \
            af[_m][_k], bfx[_n][_k], acc[(mh)*4+_m][(nh)*2+_n], 0, 0, 0);           \
  __builtin_amdgcn_s_setprio(0);                                                    \
} while (0)

__global__ __launch_bounds__(512, 2) void gemm_v(
    const unsigned short* __restrict__ A, const unsigned short* __restrict__ Bt,
    unsigned short* __restrict__ vT) {
  __shared__ __align__(16) unsigned short lds[65536];
  // bijective XCD swizzle over 384 blocks (48 per XCD)
  int lin = blockIdx.y * 3 + blockIdx.x;
  int swz = (lin & 7) * 48 + (lin >> 3);
  int bm = swz / 3;
  int bj = 6 + (swz - bm * 3);                // v tiles only: bj in 6..8
  int m0 = bm * 256, j0 = bj * 256;
  int tid = threadIdx.x;
  int wid = tid >> 6, lane = tid & 63;
  int wm = wid >> 2, wn = wid & 3;
  int quad = lane >> 4, l16 = lane & 15;
  int srow = lane >> 3, sch = lane & 7;
  int cmem = sch ^ srow;
  int lanegoff = srow * 768 + cmem * 8;

  f32x4 acc[8][4];
  f32x4 z = {0.f, 0.f, 0.f, 0.f};
#pragma unroll
  for (int i = 0; i < 8; i++)
#pragma unroll
    for (int j = 0; j < 4; j++) acc[i][j] = z;

  bf16x8 af[4][2], bf0[2][2], bf1[2][2];

  const unsigned short* Ab2 = A + (size_t)m0 * 768;
  const unsigned short* Bb2 = Bt + (size_t)j0 * 768;

  STAGE(Ab2, 0, 0, 0, 0); STAGE(Bb2, 0, 1, 0, 0); STAGE(Bb2, 0, 1, 1, 0); STAGE(Ab2, 0, 0, 1, 0);
  STAGE(Ab2, 1, 0, 0, 1); STAGE(Bb2, 1, 1, 0, 1); STAGE(Bb2, 1, 1, 1, 1);
  WAITV(10);
  BARX();
  LOAD_A(0, 0);
  LOAD_B(bf0, 0, 0);
  WAITV(8);
  BARX();

  for (int t = 0; t < 10; t++) {
    int p = t & 1;
    LOAD_B(bf1, p, 1);
    STAGE(Ab2, p ^ 1, 0, 1, t + 1);
    BARX(); SCHED();
    MFMA_PH(0, 0, bf0);
    SCHED(); WAITV(8); BARX();
    STAGE(Ab2, p, 0, 0, t + 2);
    BARX(); SCHED();
    MFMA_PH(0, 1, bf1);
    SCHED();
    LOAD_A(p, 1);
    BARX();
    STAGE(Bb2, p, 1, 0, t + 2);
    BARX(); SCHED();
    MFMA_PH(1, 1, bf1);
    SCHED(); WAITV(8); BARX();
    STAGE(Bb2, p, 1, 1, t + 2);
    BARX(); SCHED();
    MFMA_PH(1, 0, bf0);
    SCHED();
    LOAD_A(p ^ 1, 0);
    LOAD_B(bf0, p ^ 1, 0);
    WAITV(8); BARX();
  }
  LOAD_B(bf1, 0, 1);
  STAGE(Ab2, 1, 0, 1, 11);
  BARX(); SCHED(); MFMA_PH(0, 0, bf0); SCHED(); WAITV(8); BARX();
  BARX(); SCHED(); MFMA_PH(0, 1, bf1); SCHED(); LOAD_A(0, 1); BARX();
  BARX(); SCHED(); MFMA_PH(1, 1, bf1); SCHED(); WAITV(4); BARX();
  BARX(); SCHED(); MFMA_PH(1, 0, bf0); SCHED(); LOAD_A(1, 0); LOAD_B(bf0, 1, 0); WAITV(2); BARX();
  LOAD_B(bf1, 1, 1);
  BARX(); SCHED(); MFMA_PH(0, 0, bf0); SCHED(); WAITV(0); BARX();
  BARX(); SCHED(); MFMA_PH(0, 1, bf1); SCHED(); LOAD_A(1, 1); BARX();
  BARX(); SCHED(); MFMA_PH(1, 1, bf1); SCHED(); BARX();
  BARX(); SCHED(); MFMA_PH(1, 0, bf0); SCHED(); BARX();

  // epilogue: v only -> vT [b*8+h][n][e]
  int b = m0 >> 12;
  int n0 = m0 & 4095;
  int j0v = j0 - 1536;
#pragma unroll
  for (int mh = 0; mh < 2; mh++) {
    __syncthreads();
#pragma unroll
    for (int ml = 0; ml < 4; ml++) {
      int mi = mh * 4 + ml;
      int mloc = wm * 64 + ml * 16 + quad * 4;
#pragma unroll
      for (int ni = 0; ni < 4; ni++) {
        int jc = (ni >> 1) * 128 + wn * 32 + (ni & 1) * 16 + l16;
#pragma unroll
        for (int r = 0; r < 4; r++) lds[(mloc + r) * 264 + jc] = f2b(acc[mi][ni][r]);
      }
    }
    __syncthreads();
#pragma unroll
    for (int it = 0; it < 8; it++) {
      int id = it * 512 + tid;
      int mr = id >> 5, ch = id & 31;
      int cp = j0v + ch * 8;
      int hh = cp / 96, e = cp - hh * 96;
      size_t off = ((size_t)(b * 8 + hh) * 4096 + (n0 + mh * 128 + mr)) * 96 + e;
      *(uint4*)&vT[off] = *(const uint4*)&lds[mr * 264 + ch * 8];
    }
  }
}

// ---------------- gemm_g: G_b = x_b^T x_b (bf16 out), 128^2 2-phase ----------------
__global__ __launch_bounds__(256, 2) void gemm_g(
    const unsigned short* __restrict__ xbT, unsigned short* __restrict__ G) {
  __shared__ __align__(16) unsigned short lds[16384];
  int bj = blockIdx.x;                      // 0..5
  int bz = blockIdx.y;                      // 0..47
  int b = bz / 6, mt = bz - b * 6;
  int m0 = mt * 128, j0 = bj * 128;
  int tid = threadIdx.x;
  int wid = tid >> 6, lane = tid & 63;
  int wm = wid >> 1, wn = wid & 1;
  int quad = lane >> 4, l16 = lane & 15;
  int srow = lane >> 3, sch = lane & 7;
  int cmem = sch ^ srow;

  f32x4 acc[4][4];
  f32x4 z = {0.f, 0.f, 0.f, 0.f};
#pragma unroll
  for (int i = 0; i < 4; i++)
#pragma unroll
    for (int j = 0; j < 4; j++) acc[i][j] = z;

  const unsigned short* Ab = xbT + ((size_t)b * 768 + m0) * 4096;
  const unsigned short* Bb = xbT + ((size_t)b * 768 + j0) * 4096;

  for (int k0 = 0; k0 < 4096; k0 += 64) {
#pragma unroll
    for (int i = 0; i < 4; i++) {
      int ig = wid * 4 + i;
      int row = ig * 8 + srow;
      gload16(Ab + (size_t)row * 4096 + k0 + cmem * 8, &lds[ig * 512]);
      gload16(Bb + (size_t)row * 4096 + k0 + cmem * 8, &lds[8192 + ig * 512]);
    }
    __syncthreads();
#pragma unroll
    for (int kk = 0; kk < 2; kk++) {
      int cs = ((kk * 4 + quad) ^ (l16 & 7)) * 8;
      bf16x8 af[4], bfr[4];
#pragma unroll
      for (int mi = 0; mi < 4; mi++)
        af[mi] = *(const bf16x8*)&lds[(wm * 64 + mi * 16 + l16) * 64 + cs];
#pragma unroll
      for (int ni = 0; ni < 4; ni++)
        bfr[ni] = *(const bf16x8*)&lds[8192 + (wn * 64 + ni * 16 + l16) * 64 + cs];
#pragma unroll
      for (int mi = 0; mi < 4; mi++)
#pragma unroll
        for (int ni = 0; ni < 4; ni++)
          acc[mi][ni] = __builtin_amdgcn_mfma_f32_16x16x32_bf16(af[mi], bfr[ni], acc[mi][ni], 0, 0, 0);
    }
    __syncthreads();
  }
  unsigned short* Gb = G + ((size_t)b * 768 + m0) * 768 + j0;
#pragma unroll
  for (int ni = 0; ni < 4; ni++)
#pragma unroll
    for (int mi = 0; mi < 4; mi++)
#pragma unroll
      for (int r = 0; r < 4; r++)
        Gb[(size_t)(wm * 64 + mi * 16 + quad * 4 + r) * 768 + wn * 64 + ni * 16 + l16] =
            f2b(acc[mi][ni][r]);
}

// ---------------- gemm_t12: T12t[b][j][c] = (G_b @ [Wq|Wk])^T, transposed store ----------------
__global__ __launch_bounds__(256, 2) void gemm_t12(
    const unsigned short* __restrict__ G, const unsigned short* __restrict__ WqkvT,
    unsigned short* __restrict__ T12t) {
  __shared__ __align__(16) unsigned short lds[17408];
  int bj = blockIdx.x;                      // 0..11
  int bz = blockIdx.y;                      // 0..47
  int b = bz / 6, mt = bz - b * 6;
  int m0 = mt * 128, j0 = bj * 128;
  int tid = threadIdx.x;
  int wid = tid >> 6, lane = tid & 63;
  int wm = wid >> 1, wn = wid & 1;
  int quad = lane >> 4, l16 = lane & 15;
  int srow = lane >> 3, sch = lane & 7;
  int cmem = sch ^ srow;

  f32x4 acc[4][4];
  f32x4 z = {0.f, 0.f, 0.f, 0.f};
#pragma unroll
  for (int i = 0; i < 4; i++)
#pragma unroll
    for (int j = 0; j < 4; j++) acc[i][j] = z;

  const unsigned short* Ab = G + ((size_t)b * 768 + m0) * 768;
  const unsigned short* Bb = WqkvT + (size_t)j0 * 768;

  for (int k0 = 0; k0 < 768; k0 += 64) {
#pragma unroll
    for (int i = 0; i < 4; i++) {
      int ig = wid * 4 + i;
      int row = ig * 8 + srow;
      gload16(Ab + (size_t)row * 768 + k0 + cmem * 8, &lds[ig * 512]);
      gload16(Bb + (size_t)row * 768 + k0 + cmem * 8, &lds[8192 + ig * 512]);
    }
    __syncthreads();
#pragma unroll
    for (int kk = 0; kk < 2; kk++) {
      int cs = ((kk * 4 + quad) ^ (l16 & 7)) * 8;
      bf16x8 af[4], bfr[4];
#pragma unroll
      for (int mi = 0; mi < 4; mi++)
        af[mi] = *(const bf16x8*)&lds[(wm * 64 + mi * 16 + l16) * 64 + cs];
#pragma unroll
      for (int ni = 0; ni < 4; ni++)
        bfr[ni] = *(const bf16x8*)&lds[8192 + (wn * 64 + ni * 16 + l16) * 64 + cs];
#pragma unroll
      for (int mi = 0; mi < 4; mi++)
#pragma unroll
        for (int ni = 0; ni < 4; ni++)
          acc[mi][ni] = __builtin_amdgcn_mfma_f32_16x16x32_bf16(af[mi], bfr[ni], acc[mi][ni], 0, 0, 0);
    }
    __syncthreads();
  }
  // transpose bounce [128 j][136] then store T12t rows
#pragma unroll
  for (int mi = 0; mi < 4; mi++)
#pragma unroll
    for (int ni = 0; ni < 4; ni++)
#pragma unroll
      for (int r = 0; r < 4; r++) {
        int m = wm * 64 + mi * 16 + quad * 4 + r;
        int cc = wn * 64 + ni * 16 + l16;
        lds[cc * 136 + m] = f2b(acc[mi][ni][r]);
      }
  __syncthreads();
#pragma unroll
  for (int it = 0; it < 8; it++) {
    int id = tid + it * 256;
    int jr = id >> 4, mc = id & 15;
    *(uint4*)&T12t[((size_t)b * 1536 + j0 + jr) * 768 + m0 + mc * 8] =
        *(const uint4*)&lds[jr * 136 + mc * 8];
  }
}

// ---------------- softmax_s: per bh, S = T2_h^T @ Wk_h + normsq diag dots + softmax ----------------
__global__ __launch_bounds__(256, 2) void softmax_s(
    const unsigned short* __restrict__ T12t, const unsigned short* __restrict__ WqkvT,
    const float* __restrict__ temp, unsigned short* __restrict__ attnB) {
  // panels (96x64 each): PA(T2t)@0, PW1(Wq)@6144, PA2(T1t)@12288, PW2(Wk)@18432
  // after K-loop: Sf f32[96][97] aliases panels; nq@24576, nk@24768 (shorts)
  __shared__ __align__(16) unsigned short lds[24960];
  float* nq = (float*)&lds[24576];
  float* nk = (float*)&lds[24768];
  int bh = blockIdx.x;
  int b = bh >> 3, h = bh & 7;
  int tid = threadIdx.x, wid = tid >> 6, lane = tid & 63;
  int wm = wid >> 1, wn = wid & 1, quad = lane >> 4, l16 = lane & 15;
  int srow = lane >> 3, sch = lane & 7, cmem = sch ^ srow;

  const unsigned short* pb0 = T12t + ((size_t)b * 1536 + h * 96) * 768;        // T2t rows (d)
  const unsigned short* pb1 = WqkvT + (size_t)(h * 96) * 768;                  // Wq^T rows (d)
  const unsigned short* pb2 = T12t + ((size_t)b * 1536 + 768 + h * 96) * 768;  // T1t rows (e)
  const unsigned short* pb3 = WqkvT + (size_t)(768 + h * 96) * 768;            // Wk^T rows (e)

  f32x4 acc[3][3];
  f32x4 z = {0.f, 0.f, 0.f, 0.f};
#pragma unroll
  for (int i = 0; i < 3; i++)
#pragma unroll
    for (int j = 0; j < 3; j++) acc[i][j] = z;
  float aq[3] = {0.f, 0.f, 0.f}, ak[3] = {0.f, 0.f, 0.f};

  for (int k0 = 0; k0 < 768; k0 += 64) {
#pragma unroll
    for (int i = 0; i < 3; i++) {
      int igrp = wid * 3 + i;              // 0..11 (8 rows each -> 96 rows)
      int row = igrp * 8 + srow;
      size_t off = (size_t)row * 768 + k0 + cmem * 8;
      gload16(pb0 + off, &lds[igrp * 512]);
      gload16(pb1 + off, &lds[6144 + igrp * 512]);
      gload16(pb2 + off, &lds[12288 + igrp * 512]);
      gload16(pb3 + off, &lds[18432 + igrp * 512]);
    }
    __syncthreads();
#pragma unroll
    for (int kk = 0; kk < 2; kk++) {
      int cs = ((kk * 4 + quad) ^ (l16 & 7)) * 8;
      bf16x8 af[3], bfr[3];
#pragma unroll
      for (int mi = 0; mi < 3; mi++)
        af[mi] = *(const bf16x8*)&lds[(wm * 48 + mi * 16 + l16) * 64 + cs];
#pragma unroll
      for (int ni = 0; ni < 3; ni++)
        bfr[ni] = *(const bf16x8*)&lds[18432 + (wn * 48 + ni * 16 + l16) * 64 + cs];
#pragma unroll
      for (int mi = 0; mi < 3; mi++)
#pragma unroll
        for (int ni = 0; ni < 3; ni++)
          acc[mi][ni] = __builtin_amdgcn_mfma_f32_16x16x32_bf16(af[mi], bfr[ni], acc[mi][ni], 0, 0, 0);
    }
    // normsq row-dots (chunk permutation identical in both panels -> sum invariant)
#pragma unroll
    for (int s = 0; s < 3; s++) {
      int idx = s * 256 + tid;
      int r = idx >> 3, ch = idx & 7;
      aq[s] += dot8(&lds[r * 64 + ch * 8], &lds[6144 + r * 64 + ch * 8]);
      ak[s] += dot8(&lds[12288 + r * 64 + ch * 8], &lds[18432 + r * 64 + ch * 8]);
    }
    __syncthreads();
  }
  // 8-lane reduce -> nq/nk
#pragma unroll
  for (int s = 0; s < 3; s++) {
    float vq = aq[s], vk = ak[s];
    vq += __shfl_down(vq, 4, 8); vq += __shfl_down(vq, 2, 8); vq += __shfl_down(vq, 1, 8);
    vk += __shfl_down(vk, 4, 8); vk += __shfl_down(vk, 2, 8); vk += __shfl_down(vk, 1, 8);
    if ((tid & 7) == 0) { nq[s * 32 + (tid >> 3)] = vq; nk[s * 32 + (tid >> 3)] = vk; }
  }
  __syncthreads();
  // S -> Sf (aliases panels, all panel reads done)
  float* Sf = (float*)lds;
#pragma unroll
  for (int mi = 0; mi < 3; mi++)
#pragma unroll
    for (int ni = 0; ni < 3; ni++)
#pragma unroll
      for (int r = 0; r < 4; r++)
        Sf[(wm * 48 + mi * 16 + quad * 4 + r) * 97 + wn * 48 + ni * 16 + l16] = acc[mi][ni][r];
  if (tid < 96) nk[tid] = 1.0f / fmaxf(sqrtf(nk[tid]), 1e-12f);
  __syncthreads();
  float tval = temp[h];
  for (int r = wid; r < 96; r += 4) {
    float iq = tval / fmaxf(sqrtf(nq[r]), 1e-12f);
    float v0 = Sf[r * 97 + lane] * iq * nk[lane];
    float v1 = (lane < 32) ? Sf[r * 97 + 64 + lane] * iq * nk[64 + lane] : -1e30f;
    float mx = fmaxf(v0, v1);
#pragma unroll
    for (int off = 32; off; off >>= 1) mx = fmaxf(mx, __shfl_xor(mx, off, 64));
    float e0 = __expf(v0 - mx);
    float e1 = (lane < 32) ? __expf(v1 - mx) : 0.f;
    float sm = e0 + e1;
#pragma unroll
    for (int off = 32; off; off >>= 1) sm += __shfl_xor(sm, off, 64);
    float inv = 1.0f / sm;
    unsigned short* row = attnB + (size_t)bh * 9984 + r * 104;
    row[lane] = f2b(e0 * inv);
    if (lane < 32) row[64 + lane] = f2b(e1 * inv);
    else if (64 + lane < 104) row[64 + lane] = 0;
  }
}

// ---------------- out = attn @ v (attn pre-softmaxed) ----------------
__global__ __launch_bounds__(256, 4) void attn_v(
    const unsigned short* __restrict__ attnB, const unsigned short* __restrict__ vT,
    unsigned short* __restrict__ U) {
  __shared__ __align__(16) unsigned short lds[23552];
  int blk = blockIdx.x;
  int bh = blk >> 5, nc = blk & 31;
  int b = bh >> 3, h = bh & 7;
  int n0 = nc * 128;
  int tid = threadIdx.x, wid = tid >> 6, lane = tid & 63;
  int wm = wid >> 1, wn = wid & 1, quad = lane >> 4, l16 = lane & 15;

  const unsigned short* ab = attnB + (size_t)bh * 9984;
#pragma unroll
  for (int i = 0; i < 5; i++) {
    int id = i * 256 + tid;
    int ids = id < 1248 ? id : 1247;
    gload16(ab + (size_t)ids * 8, &lds[(i * 4 + wid) * 512]);
  }

  const unsigned short* vb = vT + (size_t)bh * 4096 * 96 + (size_t)n0 * 96;
#pragma unroll
  for (int i = 0; i < 7; i++) {
    int ig = wid + i * 4;
    if (ig < 26) {
      int id = ig * 64 + lane;
      int row = id / 13;
      int ch = id - row * 13;
      if (ch > 11) ch = 11;
      gload16(vb + (size_t)row * 96 + ch * 8, &lds[10240 + ig * 512]);
    }
  }
  __syncthreads();

  f32x4 acc[3][4];
  f32x4 z = {0.f, 0.f, 0.f, 0.f};
#pragma unroll
  for (int i = 0; i < 3; i++)
#pragma unroll
    for (int j = 0; j < 4; j++) acc[i][j] = z;
#pragma unroll
  for (int et = 0; et < 3; et++) {
    bf16x8 af[3], bfr[4];
#pragma unroll
    for (int mi = 0; mi < 3; mi++)
      af[mi] = *(const bf16x8*)&lds[(wm * 48 + mi * 16 + l16) * 104 + (et * 4 + quad) * 8];
#pragma unroll
    for (int ni = 0; ni < 4; ni++)
      bfr[ni] = *(const bf16x8*)&lds[10240 + (wn * 64 + ni * 16 + l16) * 104 + (et * 4 + quad) * 8];
#pragma unroll
    for (int mi = 0; mi < 3; mi++)
#pragma unroll
      for (int ni = 0; ni < 4; ni++)
        acc[mi][ni] = __builtin_amdgcn_mfma_f32_16x16x32_bf16(af[mi], bfr[ni], acc[mi][ni], 0, 0, 0);
  }
  __syncthreads();

#pragma unroll
  for (int mi = 0; mi < 3; mi++)
#pragma unroll
    for (int ni = 0; ni < 4; ni++)
#pragma unroll
      for (int r = 0; r < 4; r++) {
        int d = wm * 48 + mi * 16 + quad * 4 + r;
        int n = wn * 64 + ni * 16 + l16;
        lds[n * 104 + d] = f2b(acc[mi][ni][r]);
      }
  __syncthreads();
#pragma unroll
  for (int it = 0; it < 6; it++) {
    int id = tid + it * 256;
    int nr = id / 12, ch = id - nr * 12;
    *(uint4*)&U[((size_t)(b * 4096 + n0 + nr)) * 768 + h * 96 + ch * 8] =
        *(const uint4*)&lds[nr * 104 + ch * 8];
  }
}

// ---------------- GEMM3: y = U @ Wproj + bproj ----------------
__global__ __launch_bounds__(256, 2) void gemm_out(
    const unsigned short* __restrict__ A, const unsigned short* __restrict__ Bt,
    const float* __restrict__ bias, float* __restrict__ out) {
  __shared__ __align__(16) unsigned short lds[16384];
  int bj = blockIdx.x;
  int bm = blockIdx.y;
  int m0 = bm * 128, j0 = bj * 128;
  int tid = threadIdx.x;
  int wid = tid >> 6, lane = tid & 63;
  int wm = wid >> 1, wn = wid & 1;
  int quad = lane >> 4, l16 = lane & 15;
  int srow = lane >> 3, sch = lane & 7;
  int cmem = sch ^ srow;

  f32x4 acc[4][4];
  f32x4 z = {0.f, 0.f, 0.f, 0.f};
#pragma unroll
  for (int i = 0; i < 4; i++)
#pragma unroll
    for (int j = 0; j < 4; j++) acc[i][j] = z;

  const unsigned short* Ab = A + (size_t)m0 * 768;
  const unsigned short* Bb = Bt + (size_t)j0 * 768;

  for (int k0 = 0; k0 < 768; k0 += 64) {
#pragma unroll
    for (int i = 0; i < 4; i++) {
      int ig = wid * 4 + i;
      int row = ig * 8 + srow;
      gload16(Ab + (size_t)row * 768 + k0 + cmem * 8, &lds[ig * 512]);
      gload16(Bb + (size_t)row * 768 + k0 + cmem * 8, &lds[8192 + ig * 512]);
    }
    __syncthreads();
#pragma unroll
    for (int kk = 0; kk < 2; kk++) {
      int cs = ((kk * 4 + quad) ^ (l16 & 7)) * 8;
      bf16x8 af[4], bfr[4];
#pragma unroll
      for (int mi = 0; mi < 4; mi++)
        af[mi] = *(const bf16x8*)&lds[(wm * 64 + mi * 16 + l16) * 64 + cs];
#pragma unroll
      for (int ni = 0; ni < 4; ni++)
        bfr[ni] = *(const bf16x8*)&lds[8192 + (wn * 64 + ni * 16 + l16) * 64 + cs];
#pragma unroll
      for (int mi = 0; mi < 4; mi++)
#pragma unroll
        for (int ni = 0; ni < 4; ni++)
          acc[mi][ni] = __builtin_amdgcn_mfma_f32_16x16x32_bf16(af[mi], bfr[ni], acc[mi][ni], 0, 0, 0);
    }
    __syncthreads();
  }
#pragma unroll
  for (int ni = 0; ni < 4; ni++) {
    int ccol = j0 + wn * 64 + ni * 16 + l16;
    float bv = bias[ccol];
#pragma unroll
    for (int mi = 0; mi < 4; mi++)
#pragma unroll
      for (int r = 0; r < 4; r++)
        out[(size_t)(m0 + wm * 64 + mi * 16 + quad * 4 + r) * 768 + ccol] = acc[mi][ni][r] + bv;
  }
}

// ---------------- host ----------------
extern "C" void kernel_launch(void* const* d_in, const int* in_sizes, int n_in,
                              void* d_out, int out_size, void* d_ws, size_t ws_size,
                              hipStream_t stream) {
  const float* x = (const float*)d_in[0];
  const float* Wqkv = (const float*)d_in[1];
  const float* temp = (const float*)d_in[2];
  const float* Wproj = (const float*)d_in[3];
  const float* bproj = (const float*)d_in[4];
  float* out = (float*)d_out;
  char* ws = (char*)d_ws;

  unsigned short* xb     = (unsigned short*)(ws);                 // 50331648 B
  unsigned short* WqkvT  = (unsigned short*)(ws + 50331648);      // 3538944
  unsigned short* WprojT = (unsigned short*)(ws + 53870592);      // 1179648
  unsigned short* xbT    = (unsigned short*)(ws + 55050240);      // 50331648
  unsigned short* vT     = (unsigned short*)(ws + 105381888);     // 50331648
  unsigned short* U      = (unsigned short*)(ws + 155713536);     // 50331648
  unsigned short* G      = (unsigned short*)(ws + 206045184);     // 9437184
  unsigned short* T12t   = (unsigned short*)(ws + 215482368);     // 18874368
  unsigned short* attnB  = (unsigned short*)(ws + 234356736);     // 1277952

  cvt_x<<<dim3(24, 128, 8), dim3(256), 0, stream>>>(x, xb, xbT);
  cvt_transpose<<<dim3(72, 24), dim3(256), 0, stream>>>(Wqkv, WqkvT, 768, 2304);
  cvt_transpose<<<dim3(24, 24), dim3(256), 0, stream>>>(Wproj, WprojT, 768, 768);
  gemm_g<<<dim3(6, 48), dim3(256), 0, stream>>>(xbT, G);
  gemm_t12<<<dim3(12, 48), dim3(256), 0, stream>>>(G, WqkvT, T12t);
  softmax_s<<<dim3(64), dim3(256), 0, stream>>>(T12t, WqkvT, temp, attnB);
  gemm_v<<<dim3(3, 128), dim3(512), 0, stream>>>(xb, WqkvT, vT);
  attn_v<<<dim3(2048), dim3(256), 0, stream>>>(attnB, vT, U);
  gemm_out<<<dim3(6, 256), dim3(256), 0, stream>>>(U, WprojT, bproj, out);
}

// Round 6
// 415.365 us; speedup vs baseline: 1.1187x; 1.1187x over previous
//
#include <hip/hip_runtime.h>
#include <stdint.h>

// B=8, N=4096, C=768, H=8, hd=96. bf16 MFMA path.
// G-route: S_bh = Wq_h^T G_b Wk_h with G_b = x_b^T x_b (symmetric: lower-tri tiles + mirror).
// gemm_gv = fused launch: 168 symmetric-G blocks (K=4096) + 1536 v-GEMM 128^2 blocks,
// co-resident 2/CU so G's HBM latency hides under v's MFMA.
// LDS tiles row-major [rows][8 chunks of 8] with XOR chunk swizzle (conflict-free b128).

typedef __attribute__((ext_vector_type(8))) __bf16 bf16x8;
typedef __attribute__((ext_vector_type(4))) float f32x4;

__device__ __forceinline__ unsigned short f2b(float f) {
  uint32_t u = __float_as_uint(f);
  u += 0x7FFF + ((u >> 16) & 1);
  return (unsigned short)(u >> 16);
}

__device__ __forceinline__ void gload16(const void* g, void* l) {
  __builtin_amdgcn_global_load_lds(
      (__attribute__((address_space(1))) void*)(uintptr_t)g,
      (__attribute__((address_space(3))) void*)(uintptr_t)l, 16, 0, 0);
}

__device__ __forceinline__ float dot8(const unsigned short* a, const unsigned short* b) {
  uint4 va = *(const uint4*)a, vb = *(const uint4*)b;
  const unsigned short* pa = (const unsigned short*)&va;
  const unsigned short* pb = (const unsigned short*)&vb;
  float s = 0.f;
#pragma unroll
  for (int i = 0; i < 8; i++)
    s += __uint_as_float((uint32_t)pa[i] << 16) * __uint_as_float((uint32_t)pb[i] << 16);
  return s;
}

// ---------------- cvt_x: x -> xb [bn][c] and xbT [b][c][n], 64x64 tiles ----------------
__global__ __launch_bounds__(256) void cvt_x(const float* __restrict__ in,
                                             unsigned short* __restrict__ xb,
                                             unsigned short* __restrict__ xbT) {
  __shared__ unsigned short tileT[64][66];  // [c][n], stride 66 (~2-way banks, 8B-aligned rows every other)
  int c0 = blockIdx.x * 64, n0 = blockIdx.y * 64, b = blockIdx.z;
  int tid = threadIdx.x;
  int col4 = tid & 15, rbase = tid >> 4;    // 16 col-chunks x 16 rows
  const float* src = in + (size_t)b * 4096 * 768;
#pragma unroll
  for (int rr = 0; rr < 4; rr++) {
    int r = rr * 16 + rbase;                // n-row
    float4 v = *(const float4*)&src[(size_t)(n0 + r) * 768 + c0 + col4 * 4];
    ushort4 o;
    o.x = f2b(v.x); o.y = f2b(v.y); o.z = f2b(v.z); o.w = f2b(v.w);
    *(ushort4*)&xb[((size_t)b * 4096 + n0 + r) * 768 + c0 + col4 * 4] = o;
    tileT[col4 * 4 + 0][r] = o.x;
    tileT[col4 * 4 + 1][r] = o.y;
    tileT[col4 * 4 + 2][r] = o.z;
    tileT[col4 * 4 + 3][r] = o.w;
  }
  __syncthreads();
#pragma unroll
  for (int rr = 0; rr < 4; rr++) {
    int cc = rr * 16 + rbase;               // c-row
    ushort4 w;
    w.x = tileT[cc][col4 * 4 + 0];
    w.y = tileT[cc][col4 * 4 + 1];
    w.z = tileT[cc][col4 * 4 + 2];
    w.w = tileT[cc][col4 * 4 + 3];
    *(ushort4*)&xbT[((size_t)b * 768 + c0 + cc) * 4096 + n0 + col4 * 4] = w;
  }
}

// ---------------- cvt_w: both weight transposes in one launch ----------------
__global__ __launch_bounds__(256) void cvt_w(const float* __restrict__ Wqkv,
                                             const float* __restrict__ Wproj,
                                             unsigned short* __restrict__ WqkvT,
                                             unsigned short* __restrict__ WprojT) {
  __shared__ float tile[32][33];
  int z = blockIdx.z;
  const float* in = z ? Wproj : Wqkv;
  unsigned short* out = z ? WprojT : WqkvT;
  int NC = z ? 768 : 2304;
  if (z && blockIdx.x >= 24) return;
  int bx = blockIdx.x, by = blockIdx.y;
  int tx = threadIdx.x & 31, ty = threadIdx.x >> 5;
  for (int r = ty; r < 32; r += 8)
    tile[r][tx] = in[(size_t)(by * 32 + r) * NC + bx * 32 + tx];
  __syncthreads();
  for (int r = ty; r < 32; r += 8)
    out[(size_t)(bx * 32 + r) * 768 + by * 32 + tx] = f2b(tile[tx][r]);
}

// ---------------- gemm_gv: fused G (symmetric) + v GEMM ----------------
// blocks 0..167: G_b lower-tri 128^2 tiles, K=4096, mirror write.
// blocks 168..1703: v = x @ Wv, 128^2, K=768, scatter to vT[bh][n][e].
__global__ __launch_bounds__(256, 2) void gemm_gv(
    const unsigned short* __restrict__ xbT, const unsigned short* __restrict__ xb,
    const unsigned short* __restrict__ WqkvT, unsigned short* __restrict__ G,
    unsigned short* __restrict__ vT) {
  __shared__ __align__(16) unsigned short lds[17408];  // staging 16384; bounce [128][136]
  int tid = threadIdx.x;
  int wid = tid >> 6, lane = tid & 63;
  int wm = wid >> 1, wn = wid & 1;
  int quad = lane >> 4, l16 = lane & 15;
  int srow = lane >> 3, sch = lane & 7;
  int cmem = sch ^ srow;

  f32x4 acc[4][4];
  f32x4 z = {0.f, 0.f, 0.f, 0.f};
#pragma unroll
  for (int i = 0; i < 4; i++)
#pragma unroll
    for (int j = 0; j < 4; j++) acc[i][j] = z;

  if (blockIdx.x < 168) {
    // ---- G branch: XCD-chunked (168 = 8*21, each XCD owns one batch's triangle) ----
    int lin = blockIdx.x;
    int widx = (lin & 7) * 21 + (lin >> 3);
    int b = widx / 21, ti = widx - b * 21;
    int mt = 0;
    while ((mt + 1) * (mt + 2) / 2 <= ti) mt++;
    int jt = ti - mt * (mt + 1) / 2;
    int m0 = mt * 128, j0 = jt * 128;
    const unsigned short* Ab = xbT + ((size_t)b * 768 + m0) * 4096;
    const unsigned short* Bb = xbT + ((size_t)b * 768 + j0) * 4096;

    for (int k0 = 0; k0 < 4096; k0 += 64) {
#pragma unroll
      for (int i = 0; i < 4; i++) {
        int ig = wid * 4 + i;
        int row = ig * 8 + srow;
        gload16(Ab + (size_t)row * 4096 + k0 + cmem * 8, &lds[ig * 512]);
        gload16(Bb + (size_t)row * 4096 + k0 + cmem * 8, &lds[8192 + ig * 512]);
      }
      __syncthreads();
#pragma unroll
      for (int kk = 0; kk < 2; kk++) {
        int cs = ((kk * 4 + quad) ^ (l16 & 7)) * 8;
        bf16x8 af[4], bfr[4];
#pragma unroll
        for (int mi = 0; mi < 4; mi++)
          af[mi] = *(const bf16x8*)&lds[(wm * 64 + mi * 16 + l16) * 64 + cs];
#pragma unroll
        for (int ni = 0; ni < 4; ni++)
          bfr[ni] = *(const bf16x8*)&lds[8192 + (wn * 64 + ni * 16 + l16) * 64 + cs];
#pragma unroll
        for (int mi = 0; mi < 4; mi++)
#pragma unroll
          for (int ni = 0; ni < 4; ni++)
            acc[mi][ni] = __builtin_amdgcn_mfma_f32_16x16x32_bf16(af[mi], bfr[ni], acc[mi][ni], 0, 0, 0);
      }
      __syncthreads();
    }
    // direct write G[m0+m][j0+cc]
    unsigned short* Gb = G + ((size_t)b * 768 + m0) * 768 + j0;
#pragma unroll
    for (int ni = 0; ni < 4; ni++)
#pragma unroll
      for (int mi = 0; mi < 4; mi++)
#pragma unroll
        for (int r = 0; r < 4; r++)
          Gb[(size_t)(wm * 64 + mi * 16 + quad * 4 + r) * 768 + wn * 64 + ni * 16 + l16] =
              f2b(acc[mi][ni][r]);
    if (mt != jt) {
      // mirror: transpose-bounce then write G[j0+jr][m0+mc*8..]
      __syncthreads();
#pragma unroll
      for (int mi = 0; mi < 4; mi++)
#pragma unroll
        for (int ni = 0; ni < 4; ni++)
#pragma unroll
          for (int r = 0; r < 4; r++) {
            int m = wm * 64 + mi * 16 + quad * 4 + r;
            int cc = wn * 64 + ni * 16 + l16;
            lds[cc * 136 + m] = f2b(acc[mi][ni][r]);
          }
      __syncthreads();
#pragma unroll
      for (int it = 0; it < 8; it++) {
        int id = tid + it * 256;
        int jr = id >> 4, mc = id & 15;
        *(uint4*)&G[((size_t)b * 768 + j0 + jr) * 768 + m0 + mc * 8] =
            *(const uint4*)&lds[jr * 136 + mc * 8];
      }
    }
  } else {
    // ---- v branch: 128^2, K=768 ----
    int lin2 = blockIdx.x - 168;            // 0..1535
    int bm = lin2 / 6, jt = lin2 - bm * 6;  // A-major: 6 consecutive share A-panel
    int m0 = bm * 128, j0 = jt * 128;
    const unsigned short* Ab = xb + (size_t)m0 * 768;
    const unsigned short* Bb = WqkvT + (size_t)(1536 + j0) * 768;

    for (int k0 = 0; k0 < 768; k0 += 64) {
#pragma unroll
      for (int i = 0; i < 4; i++) {
        int ig = wid * 4 + i;
        int row = ig * 8 + srow;
        gload16(Ab + (size_t)row * 768 + k0 + cmem * 8, &lds[ig * 512]);
        gload16(Bb + (size_t)row * 768 + k0 + cmem * 8, &lds[8192 + ig * 512]);
      }
      __syncthreads();
#pragma unroll
      for (int kk = 0; kk < 2; kk++) {
        int cs = ((kk * 4 + quad) ^ (l16 & 7)) * 8;
        bf16x8 af[4], bfr[4];
#pragma unroll
        for (int mi = 0; mi < 4; mi++)
          af[mi] = *(const bf16x8*)&lds[(wm * 64 + mi * 16 + l16) * 64 + cs];
#pragma unroll
        for (int ni = 0; ni < 4; ni++)
          bfr[ni] = *(const bf16x8*)&lds[8192 + (wn * 64 + ni * 16 + l16) * 64 + cs];
#pragma unroll
        for (int mi = 0; mi < 4; mi++)
#pragma unroll
          for (int ni = 0; ni < 4; ni++)
            acc[mi][ni] = __builtin_amdgcn_mfma_f32_16x16x32_bf16(af[mi], bfr[ni], acc[mi][ni], 0, 0, 0);
      }
      __syncthreads();
    }
    // bounce [128 n][136] then scatter vT[(b*8+hh)][n0+mr][e]
    int b = m0 >> 12;
    int n0 = m0 & 4095;
#pragma unroll
    for (int mi = 0; mi < 4; mi++)
#pragma unroll
      for (int ni = 0; ni < 4; ni++)
#pragma unroll
        for (int r = 0; r < 4; r++) {
          int m = wm * 64 + mi * 16 + quad * 4 + r;
          int cc = wn * 64 + ni * 16 + l16;
          lds[m * 136 + cc] = f2b(acc[mi][ni][r]);
        }
    __syncthreads();
#pragma unroll
    for (int it = 0; it < 8; it++) {
      int id = tid + it * 256;
      int mr = id >> 4, ch = id & 15;
      int cp = j0 + ch * 8;
      int hh = cp / 96, e = cp - hh * 96;
      size_t off = ((size_t)(b * 8 + hh) * 4096 + (n0 + mr)) * 96 + e;
      *(uint4*)&vT[off] = *(const uint4*)&lds[mr * 136 + ch * 8];
    }
  }
}

// ---------------- gemm_t12: T12t[b][j][c] = (G_b @ [Wq|Wk])^T, transposed store ----------------
__global__ __launch_bounds__(256, 2) void gemm_t12(
    const unsigned short* __restrict__ G, const unsigned short* __restrict__ WqkvT,
    unsigned short* __restrict__ T12t) {
  __shared__ __align__(16) unsigned short lds[17408];
  int bj = blockIdx.x;                      // 0..11
  int bz = blockIdx.y;                      // 0..47
  int b = bz / 6, mt = bz - b * 6;
  int m0 = mt * 128, j0 = bj * 128;
  int tid = threadIdx.x;
  int wid = tid >> 6, lane = tid & 63;
  int wm = wid >> 1, wn = wid & 1;
  int quad = lane >> 4, l16 = lane & 15;
  int srow = lane >> 3, sch = lane & 7;
  int cmem = sch ^ srow;

  f32x4 acc[4][4];
  f32x4 z = {0.f, 0.f, 0.f, 0.f};
#pragma unroll
  for (int i = 0; i < 4; i++)
#pragma unroll
    for (int j = 0; j < 4; j++) acc[i][j] = z;

  const unsigned short* Ab = G + ((size_t)b * 768 + m0) * 768;
  const unsigned short* Bb = WqkvT + (size_t)j0 * 768;

  for (int k0 = 0; k0 < 768; k0 += 64) {
#pragma unroll
    for (int i = 0; i < 4; i++) {
      int ig = wid * 4 + i;
      int row = ig * 8 + srow;
      gload16(Ab + (size_t)row * 768 + k0 + cmem * 8, &lds[ig * 512]);
      gload16(Bb + (size_t)row * 768 + k0 + cmem * 8, &lds[8192 + ig * 512]);
    }
    __syncthreads();
#pragma unroll
    for (int kk = 0; kk < 2; kk++) {
      int cs = ((kk * 4 + quad) ^ (l16 & 7)) * 8;
      bf16x8 af[4], bfr[4];
#pragma unroll
      for (int mi = 0; mi < 4; mi++)
        af[mi] = *(const bf16x8*)&lds[(wm * 64 + mi * 16 + l16) * 64 + cs];
#pragma unroll
      for (int ni = 0; ni < 4; ni++)
        bfr[ni] = *(const bf16x8*)&lds[8192 + (wn * 64 + ni * 16 + l16) * 64 + cs];
#pragma unroll
      for (int mi = 0; mi < 4; mi++)
#pragma unroll
        for (int ni = 0; ni < 4; ni++)
          acc[mi][ni] = __builtin_amdgcn_mfma_f32_16x16x32_bf16(af[mi], bfr[ni], acc[mi][ni], 0, 0, 0);
    }
    __syncthreads();
  }
  // transpose bounce [128 j][136] then store T12t rows
#pragma unroll
  for (int mi = 0; mi < 4; mi++)
#pragma unroll
    for (int ni = 0; ni < 4; ni++)
#pragma unroll
      for (int r = 0; r < 4; r++) {
        int m = wm * 64 + mi * 16 + quad * 4 + r;
        int cc = wn * 64 + ni * 16 + l16;
        lds[cc * 136 + m] = f2b(acc[mi][ni][r]);
      }
  __syncthreads();
#pragma unroll
  for (int it = 0; it < 8; it++) {
    int id = tid + it * 256;
    int jr = id >> 4, mc = id & 15;
    *(uint4*)&T12t[((size_t)b * 1536 + j0 + jr) * 768 + m0 + mc * 8] =
        *(const uint4*)&lds[jr * 136 + mc * 8];
  }
}

// ---------------- softmax_s: per bh, S = T2_h^T @ Wk_h + normsq diag dots + softmax ----------------
__global__ __launch_bounds__(256, 2) void softmax_s(
    const unsigned short* __restrict__ T12t, const unsigned short* __restrict__ WqkvT,
    const float* __restrict__ temp, unsigned short* __restrict__ attnB) {
  __shared__ __align__(16) unsigned short lds[24960];
  float* nq = (float*)&lds[24576];
  float* nk = (float*)&lds[24768];
  int bh = blockIdx.x;
  int b = bh >> 3, h = bh & 7;
  int tid = threadIdx.x, wid = tid >> 6, lane = tid & 63;
  int wm = wid >> 1, wn = wid & 1, quad = lane >> 4, l16 = lane & 15;
  int srow = lane >> 3, sch = lane & 7, cmem = sch ^ srow;

  const unsigned short* pb0 = T12t + ((size_t)b * 1536 + h * 96) * 768;
  const unsigned short* pb1 = WqkvT + (size_t)(h * 96) * 768;
  const unsigned short* pb2 = T12t + ((size_t)b * 1536 + 768 + h * 96) * 768;
  const unsigned short* pb3 = WqkvT + (size_t)(768 + h * 96) * 768;

  f32x4 acc[3][3];
  f32x4 z = {0.f, 0.f, 0.f, 0.f};
#pragma unroll
  for (int i = 0; i < 3; i++)
#pragma unroll
    for (int j = 0; j < 3; j++) acc[i][j] = z;
  float aq[3] = {0.f, 0.f, 0.f}, ak[3] = {0.f, 0.f, 0.f};

  for (int k0 = 0; k0 < 768; k0 += 64) {
#pragma unroll
    for (int i = 0; i < 3; i++) {
      int igrp = wid * 3 + i;
      int row = igrp * 8 + srow;
      size_t off = (size_t)row * 768 + k0 + cmem * 8;
      gload16(pb0 + off, &lds[igrp * 512]);
      gload16(pb1 + off, &lds[6144 + igrp * 512]);
      gload16(pb2 + off, &lds[12288 + igrp * 512]);
      gload16(pb3 + off, &lds[18432 + igrp * 512]);
    }
    __syncthreads();
#pragma unroll
    for (int kk = 0; kk < 2; kk++) {
      int cs = ((kk * 4 + quad) ^ (l16 & 7)) * 8;
      bf16x8 af[3], bfr[3];
#pragma unroll
      for (int mi = 0; mi < 3; mi++)
        af[mi] = *(const bf16x8*)&lds[(wm * 48 + mi * 16 + l16) * 64 + cs];
#pragma unroll
      for (int ni = 0; ni < 3; ni++)
        bfr[ni] = *(const bf16x8*)&lds[18432 + (wn * 48 + ni * 16 + l16) * 64 + cs];
#pragma unroll
      for (int mi = 0; mi < 3; mi++)
#pragma unroll
        for (int ni = 0; ni < 3; ni++)
          acc[mi][ni] = __builtin_amdgcn_mfma_f32_16x16x32_bf16(af[mi], bfr[ni], acc[mi][ni], 0, 0, 0);
    }
#pragma unroll
    for (int s = 0; s < 3; s++) {
      int idx = s * 256 + tid;
      int r = idx >> 3, ch = idx & 7;
      aq[s] += dot8(&lds[r * 64 + ch * 8], &lds[6144 + r * 64 + ch * 8]);
      ak[s] += dot8(&lds[12288 + r * 64 + ch * 8], &lds[18432 + r * 64 + ch * 8]);
    }
    __syncthreads();
  }
#pragma unroll
  for (int s = 0; s < 3; s++) {
    float vq = aq[s], vk = ak[s];
    vq += __shfl_down(vq, 4, 8); vq += __shfl_down(vq, 2, 8); vq += __shfl_down(vq, 1, 8);
    vk += __shfl_down(vk, 4, 8); vk += __shfl_down(vk, 2, 8); vk += __shfl_down(vk, 1, 8);
    if ((tid & 7) == 0) { nq[s * 32 + (tid >> 3)] = vq; nk[s * 32 + (tid >> 3)] = vk; }
  }
  __syncthreads();
  float* Sf = (float*)lds;
#pragma unroll
  for (int mi = 0; mi < 3; mi++)
#pragma unroll
    for (int ni = 0; ni < 3; ni++)
#pragma unroll
      for (int r = 0; r < 4; r++)
        Sf[(wm * 48 + mi * 16 + quad * 4 + r) * 97 + wn * 48 + ni * 16 + l16] = acc[mi][ni][r];
  if (tid < 96) nk[tid] = 1.0f / fmaxf(sqrtf(nk[tid]), 1e-12f);
  __syncthreads();
  float tval = temp[h];
  for (int r = wid; r < 96; r += 4) {
    float iq = tval / fmaxf(sqrtf(nq[r]), 1e-12f);
    float v0 = Sf[r * 97 + lane] * iq * nk[lane];
    float v1 = (lane < 32) ? Sf[r * 97 + 64 + lane] * iq * nk[64 + lane] : -1e30f;
    float mx = fmaxf(v0, v1);
#pragma unroll
    for (int off = 32; off; off >>= 1) mx = fmaxf(mx, __shfl_xor(mx, off, 64));
    float e0 = __expf(v0 - mx);
    float e1 = (lane < 32) ? __expf(v1 - mx) : 0.f;
    float sm = e0 + e1;
#pragma unroll
    for (int off = 32; off; off >>= 1) sm += __shfl_xor(sm, off, 64);
    float inv = 1.0f / sm;
    unsigned short* row = attnB + (size_t)bh * 9984 + r * 104;
    row[lane] = f2b(e0 * inv);
    if (lane < 32) row[64 + lane] = f2b(e1 * inv);
    else if (64 + lane < 104) row[64 + lane] = 0;
  }
}

// ---------------- out = attn @ v (attn pre-softmaxed) ----------------
__global__ __launch_bounds__(256, 4) void attn_v(
    const unsigned short* __restrict__ attnB, const unsigned short* __restrict__ vT,
    unsigned short* __restrict__ U) {
  __shared__ __align__(16) unsigned short lds[23552];
  int blk = blockIdx.x;
  int bh = blk >> 5, nc = blk & 31;
  int b = bh >> 3, h = bh & 7;
  int n0 = nc * 128;
  int tid = threadIdx.x, wid = tid >> 6, lane = tid & 63;
  int wm = wid >> 1, wn = wid & 1, quad = lane >> 4, l16 = lane & 15;

  const unsigned short* ab = attnB + (size_t)bh * 9984;
#pragma unroll
  for (int i = 0; i < 5; i++) {
    int id = i * 256 + tid;
    int ids = id < 1248 ? id : 1247;
    gload16(ab + (size_t)ids * 8, &lds[(i * 4 + wid) * 512]);
  }

  const unsigned short* vb = vT + (size_t)bh * 4096 * 96 + (size_t)n0 * 96;
#pragma unroll
  for (int i = 0; i < 7; i++) {
    int ig = wid + i * 4;
    if (ig < 26) {
      int id = ig * 64 + lane;
      int row = id / 13;
      int ch = id - row * 13;
      if (ch > 11) ch = 11;
      gload16(vb + (size_t)row * 96 + ch * 8, &lds[10240 + ig * 512]);
    }
  }
  __syncthreads();

  f32x4 acc[3][4];
  f32x4 z = {0.f, 0.f, 0.f, 0.f};
#pragma unroll
  for (int i = 0; i < 3; i++)
#pragma unroll
    for (int j = 0; j < 4; j++) acc[i][j] = z;
#pragma unroll
  for (int et = 0; et < 3; et++) {
    bf16x8 af[3], bfr[4];
#pragma unroll
    for (int mi = 0; mi < 3; mi++)
      af[mi] = *(const bf16x8*)&lds[(wm * 48 + mi * 16 + l16) * 104 + (et * 4 + quad) * 8];
#pragma unroll
    for (int ni = 0; ni < 4; ni++)
      bfr[ni] = *(const bf16x8*)&lds[10240 + (wn * 64 + ni * 16 + l16) * 104 + (et * 4 + quad) * 8];
#pragma unroll
    for (int mi = 0; mi < 3; mi++)
#pragma unroll
      for (int ni = 0; ni < 4; ni++)
        acc[mi][ni] = __builtin_amdgcn_mfma_f32_16x16x32_bf16(af[mi], bfr[ni], acc[mi][ni], 0, 0, 0);
  }
  __syncthreads();

#pragma unroll
  for (int mi = 0; mi < 3; mi++)
#pragma unroll
    for (int ni = 0; ni < 4; ni++)
#pragma unroll
      for (int r = 0; r < 4; r++) {
        int d = wm * 48 + mi * 16 + quad * 4 + r;
        int n = wn * 64 + ni * 16 + l16;
        lds[n * 104 + d] = f2b(acc[mi][ni][r]);
      }
  __syncthreads();
#pragma unroll
  for (int it = 0; it < 6; it++) {
    int id = tid + it * 256;
    int nr = id / 12, ch = id - nr * 12;
    *(uint4*)&U[((size_t)(b * 4096 + n0 + nr)) * 768 + h * 96 + ch * 8] =
        *(const uint4*)&lds[nr * 104 + ch * 8];
  }
}

// ---------------- GEMM3: y = U @ Wproj + bproj ----------------
__global__ __launch_bounds__(256, 2) void gemm_out(
    const unsigned short* __restrict__ A, const unsigned short* __restrict__ Bt,
    const float* __restrict__ bias, float* __restrict__ out) {
  __shared__ __align__(16) unsigned short lds[16384];
  int bj = blockIdx.x;
  int bm = blockIdx.y;
  int m0 = bm * 128, j0 = bj * 128;
  int tid = threadIdx.x;
  int wid = tid >> 6, lane = tid & 63;
  int wm = wid >> 1, wn = wid & 1;
  int quad = lane >> 4, l16 = lane & 15;
  int srow = lane >> 3, sch = lane & 7;
  int cmem = sch ^ srow;

  f32x4 acc[4][4];
  f32x4 z = {0.f, 0.f, 0.f, 0.f};
#pragma unroll
  for (int i = 0; i < 4; i++)
#pragma unroll
    for (int j = 0; j < 4; j++) acc[i][j] = z;

  const unsigned short* Ab = A + (size_t)m0 * 768;
  const unsigned short* Bb = Bt + (size_t)j0 * 768;

  for (int k0 = 0; k0 < 768; k0 += 64) {
#pragma unroll
    for (int i = 0; i < 4; i++) {
      int ig = wid * 4 + i;
      int row = ig * 8 + srow;
      gload16(Ab + (size_t)row * 768 + k0 + cmem * 8, &lds[ig * 512]);
      gload16(Bb + (size_t)row * 768 + k0 + cmem * 8, &lds[8192 + ig * 512]);
    }
    __syncthreads();
#pragma unroll
    for (int kk = 0; kk < 2; kk++) {
      int cs = ((kk * 4 + quad) ^ (l16 & 7)) * 8;
      bf16x8 af[4], bfr[4];
#pragma unroll
      for (int mi = 0; mi < 4; mi++)
        af[mi] = *(const bf16x8*)&lds[(wm * 64 + mi * 16 + l16) * 64 + cs];
#pragma unroll
      for (int ni = 0; ni < 4; ni++)
        bfr[ni] = *(const bf16x8*)&lds[8192 + (wn * 64 + ni * 16 + l16) * 64 + cs];
#pragma unroll
      for (int mi = 0; mi < 4; mi++)
#pragma unroll
        for (int ni = 0; ni < 4; ni++)
          acc[mi][ni] = __builtin_amdgcn_mfma_f32_16x16x32_bf16(af[mi], bfr[ni], acc[mi][ni], 0, 0, 0);
    }
    __syncthreads();
  }
#pragma unroll
  for (int ni = 0; ni < 4; ni++) {
    int ccol = j0 + wn * 64 + ni * 16 + l16;
    float bv = bias[ccol];
#pragma unroll
    for (int mi = 0; mi < 4; mi++)
#pragma unroll
      for (int r = 0; r < 4; r++)
        out[(size_t)(m0 + wm * 64 + mi * 16 + quad * 4 + r) * 768 + ccol] = acc[mi][ni][r] + bv;
  }
}

// ---------------- host ----------------
extern "C" void kernel_launch(void* const* d_in, const int* in_sizes, int n_in,
                              void* d_out, int out_size, void* d_ws, size_t ws_size,
                              hipStream_t stream) {
  const float* x = (const float*)d_in[0];
  const float* Wqkv = (const float*)d_in[1];
  const float* temp = (const float*)d_in[2];
  const float* Wproj = (const float*)d_in[3];
  const float* bproj = (const float*)d_in[4];
  float* out = (float*)d_out;
  char* ws = (char*)d_ws;

  unsigned short* xb     = (unsigned short*)(ws);                 // 50331648 B
  unsigned short* WqkvT  = (unsigned short*)(ws + 50331648);      // 3538944
  unsigned short* WprojT = (unsigned short*)(ws + 53870592);      // 1179648
  unsigned short* xbT    = (unsigned short*)(ws + 55050240);      // 50331648
  unsigned short* vT     = (unsigned short*)(ws + 105381888);     // 50331648
  unsigned short* U      = (unsigned short*)(ws + 155713536);     // 50331648
  unsigned short* G      = (unsigned short*)(ws + 206045184);     // 9437184
  unsigned short* T12t   = (unsigned short*)(ws + 215482368);     // 18874368
  unsigned short* attnB  = (unsigned short*)(ws + 234356736);     // 1277952

  cvt_x<<<dim3(12, 64, 8), dim3(256), 0, stream>>>(x, xb, xbT);
  cvt_w<<<dim3(72, 24, 2), dim3(256), 0, stream>>>(Wqkv, Wproj, WqkvT, WprojT);
  gemm_gv<<<dim3(1704), dim3(256), 0, stream>>>(xbT, xb, WqkvT, G, vT);
  gemm_t12<<<dim3(12, 48), dim3(256), 0, stream>>>(G, WqkvT, T12t);
  softmax_s<<<dim3(64), dim3(256), 0, stream>>>(T12t, WqkvT, temp, attnB);
  attn_v<<<dim3(2048), dim3(256), 0, stream>>>(attnB, vT, U);
  gemm_out<<<dim3(6, 256), dim3(256), 0, stream>>>(U, WprojT, bproj, out);
}